// Round 6
// baseline (344.756 us; speedup 1.0000x reference)
//
#include <hip/hip_runtime.h>

#define BB 256
#define II 1152
#define QQ 8
#define JJ 10
#define PP 16

#define BT 8             // b per block (128 threads = 8 b-lanes x 16 p-lanes)
#define IT 8             // i per block (small -> grid 4608 for TLP)
#define NBT (BB / BT)    // 32
#define NIT (II / IT)    // 144
#define XROW (IT * QQ + 4)  // 68 floats (16B-aligned rows, bank-shifted)

// ---------------------------------------------------------------------------
// 16-lane row sum via DPP (pure VALU pipe — replaces ds_swizzle shuffles).
// Rows of 16 lanes == our p-lane groups (p = tid & 15).
//   xor1: quad_perm [1,0,3,2] = 0xB1
//   xor2: quad_perm [2,3,0,1] = 0x4E
//   +4  : row_ror:4           = 0x124   (after quad sums -> sum of 8)
//   +8  : row_ror:8           = 0x128   (-> sum of 16, all lanes)
// ---------------------------------------------------------------------------
template <int CTRL>
__device__ __forceinline__ float dpp_add(float v) {
    int s = __builtin_bit_cast(int, v);
    int t = __builtin_amdgcn_update_dpp(0, s, CTRL, 0xF, 0xF, true);
    return v + __builtin_bit_cast(float, t);
}
__device__ __forceinline__ float row_sum16(float v) {
    v = dpp_add<0xB1>(v);
    v = dpp_add<0x4E>(v);
    v = dpp_add<0x124>(v);
    v = dpp_add<0x128>(v);
    return v;
}

// ---------------------------------------------------------------------------
// Fused routing pass. Thread = (b_l, p). Per i in the tile:
//   h[j] = W[j,i,p,:]·x[i,:]        (p-lanes -> contiguous 512B, coalesced)
//   bj[j] = row_sum16(v[j,p]·h[j])  (DPP, VALU pipe only)
//   c = softmax_j(bj)               (redundant across p-lanes)
//   sacc[j] += c[j]·h[j]            (same h: W read once per pass)
// No logit tensor: R=1 gets v0, R=2 gets vsum=v0+v1 (b2 = (v0+v1)·hat).
// ---------------------------------------------------------------------------
template <int R>
__global__ __launch_bounds__(128, 8) void pass_kernel(
    const float* __restrict__ X,   // [B][I][Q]
    const float* __restrict__ W,   // [J][I][P][Q]
    const float* __restrict__ V,   // R=0: null; R=1: v0; R=2: v0+v1
    float* __restrict__ S)         // [B][J][P] pre-zeroed accumulator
{
    __shared__ float xs[BT * XROW];  // ~2.2 KB

    const int bt = blockIdx.x & (NBT - 1);   // consecutive blocks share i-tile (L2 W reuse)
    const int it = blockIdx.x >> 5;
    const int b0 = bt * BT;
    const int i0 = it * IT;
    const int tid = threadIdx.x;

    // stage x tile: 8 b x 8 i x 8 q = 512 floats = 128 float4, 1 per thread
    {
        const int b_l = tid >> 4;        // 16 float4 per b-row
        const int r   = tid & 15;
        const float4 v4 = ((const float4*)(X + ((size_t)(b0 + b_l) * II + i0) * QQ))[r];
        ((float4*)(xs + b_l * XROW))[r] = v4;
    }
    __syncthreads();

    const int b_l = tid >> 4;
    const int p   = tid & 15;
    const int b   = b0 + b_l;

    float vv[JJ];
    if (R > 0) {
#pragma unroll
        for (int j = 0; j < JJ; ++j)
            vv[j] = V[((size_t)b * JJ + j) * PP + p];
    }

    float sacc[JJ];
#pragma unroll
    for (int j = 0; j < JJ; ++j) sacc[j] = 0.0f;

    for (int i = 0; i < IT; ++i) {
        const float4 a0 = *(const float4*)(xs + b_l * XROW + i * QQ);
        const float4 a1 = *(const float4*)(xs + b_l * XROW + i * QQ + 4);

        float h[JJ];
#pragma unroll
        for (int j = 0; j < JJ; ++j) {
            const float4* wp = (const float4*)(W + (((size_t)j * II + i0 + i) * PP + p) * QQ);
            const float4 w0 = wp[0];
            const float4 w1 = wp[1];
            h[j] = w0.x * a0.x + w0.y * a0.y + w0.z * a0.z + w0.w * a0.w +
                   w1.x * a1.x + w1.y * a1.y + w1.z * a1.z + w1.w * a1.w;
        }

        float c[JJ];
        if (R == 0) {
#pragma unroll
            for (int j = 0; j < JJ; ++j) c[j] = 0.1f;
        } else {
            float bj[JJ];
#pragma unroll
            for (int j = 0; j < JJ; ++j)
                bj[j] = row_sum16(vv[j] * h[j]);   // 10 independent DPP chains
            float m = bj[0];
#pragma unroll
            for (int j = 1; j < JJ; ++j) m = fmaxf(m, bj[j]);
            float sum = 0.0f;
#pragma unroll
            for (int j = 0; j < JJ; ++j) { c[j] = __expf(bj[j] - m); sum += c[j]; }
            const float inv = 1.0f / sum;
#pragma unroll
            for (int j = 0; j < JJ; ++j) c[j] *= inv;
        }

#pragma unroll
        for (int j = 0; j < JJ; ++j) sacc[j] += c[j] * h[j];
    }

#pragma unroll
    for (int j = 0; j < JJ; ++j)
        atomicAdd(&S[((size_t)b * JJ + j) * PP + p], sacc[j]);
}

// ---------------------------------------------------------------------------
// squash row of 16: v = s*|s|^2/(1+|s|^2)/sqrt(|s|^2+1e-7).
// ADD_PREV: out = squash(s) + prev (builds vsum = v1 + v0 for pass 2).
// ZERO_S: re-zero s for the next pass's atomics (replaces a memset dispatch).
// ---------------------------------------------------------------------------
template <int ZERO_S, int ADD_PREV>
__global__ __launch_bounds__(256) void squash_kernel(float* __restrict__ S,
                                                     const float* __restrict__ PREV,
                                                     float* __restrict__ V)
{
    const int idx = blockIdx.x * blockDim.x + threadIdx.x;  // (b*J + j)
    if (idx >= BB * JJ) return;
    float4* sp = (float4*)(S + idx * PP);
    float4 a = sp[0], b4 = sp[1], c4 = sp[2], d4 = sp[3];
    float s2 = a.x * a.x + a.y * a.y + a.z * a.z + a.w * a.w +
               b4.x * b4.x + b4.y * b4.y + b4.z * b4.z + b4.w * b4.w +
               c4.x * c4.x + c4.y * c4.y + c4.z * c4.z + c4.w * c4.w +
               d4.x * d4.x + d4.y * d4.y + d4.z * d4.z + d4.w * d4.w;
    const float scale = s2 / (1.0f + s2) / sqrtf(s2 + 1e-7f);
    a.x *= scale; a.y *= scale; a.z *= scale; a.w *= scale;
    b4.x *= scale; b4.y *= scale; b4.z *= scale; b4.w *= scale;
    c4.x *= scale; c4.y *= scale; c4.z *= scale; c4.w *= scale;
    d4.x *= scale; d4.y *= scale; d4.z *= scale; d4.w *= scale;
    if (ADD_PREV) {
        const float4* pp = (const float4*)(PREV + idx * PP);
        const float4 p0 = pp[0], p1 = pp[1], p2 = pp[2], p3 = pp[3];
        a.x += p0.x; a.y += p0.y; a.z += p0.z; a.w += p0.w;
        b4.x += p1.x; b4.y += p1.y; b4.z += p1.z; b4.w += p1.w;
        c4.x += p2.x; c4.y += p2.y; c4.z += p2.z; c4.w += p2.w;
        d4.x += p3.x; d4.y += p3.y; d4.z += p3.z; d4.w += p3.w;
    }
    float4* vp = (float4*)(V + idx * PP);
    vp[0] = a; vp[1] = b4; vp[2] = c4; vp[3] = d4;
    if (ZERO_S) {
        const float4 z = {0.0f, 0.0f, 0.0f, 0.0f};
        sp[0] = z; sp[1] = z; sp[2] = z; sp[3] = z;
    }
}

extern "C" void kernel_launch(void* const* d_in, const int* in_sizes, int n_in,
                              void* d_out, int out_size, void* d_ws, size_t ws_size,
                              hipStream_t stream)
{
    const float* X = (const float*)d_in[0];  // [256][1152][8]
    const float* W = (const float*)d_in[1];  // [10][1152][16][8]
    float* out = (float*)d_out;              // [256][10][16]

    float* s  = (float*)d_ws;        // 40960 floats
    float* v0 = s + BB * JJ * PP;    // 40960 floats
    float* vs = v0 + BB * JJ * PP;   // 40960 floats (vsum = v0+v1); total 480 KB

    const int grid = NBT * NIT;  // 4608 blocks of 128 threads

    (void)hipMemsetAsync(s, 0, BB * JJ * PP * sizeof(float), stream);
    pass_kernel<0><<<grid, 128, 0, stream>>>(X, W, nullptr, s);
    squash_kernel<1, 0><<<10, 256, 0, stream>>>(s, nullptr, v0);   // v0; s=0
    pass_kernel<1><<<grid, 128, 0, stream>>>(X, W, v0, s);
    squash_kernel<1, 1><<<10, 256, 0, stream>>>(s, v0, vs);        // vs = v1+v0; s=0
    pass_kernel<2><<<grid, 128, 0, stream>>>(X, W, vs, s);
    squash_kernel<0, 0><<<10, 256, 0, stream>>>(s, nullptr, out);  // output
}

// Round 7
// 229.429 us; speedup vs baseline: 1.5027x; 1.5027x over previous
//
#include <hip/hip_runtime.h>

#define BB 256
#define II 1152
#define QQ 8
#define JJ 10
#define PP 16

#define BT 8             // b per block (128 threads = 8 b-lanes x 16 p-lanes)
#define IT 8             // i per block (grid 4608 for TLP)
#define NBT (BB / BT)    // 32
#define NIT (II / IT)    // 144
#define XROW (IT * QQ + 4)  // 68 floats (16B-aligned rows, bank-shifted)

// ---------------------------------------------------------------------------
// 16-lane row sum via DPP (pure VALU pipe — no LDS-pipe ds_swizzle).
//   xor1: quad_perm [1,0,3,2] = 0xB1
//   xor2: quad_perm [2,3,0,1] = 0x4E
//   +4  : row_ror:4           = 0x124
//   +8  : row_ror:8           = 0x128   (-> sum of 16, all lanes)
// ---------------------------------------------------------------------------
template <int CTRL>
__device__ __forceinline__ float dpp_add(float v) {
    int s = __builtin_bit_cast(int, v);
    int t = __builtin_amdgcn_update_dpp(0, s, CTRL, 0xF, 0xF, true);
    return v + __builtin_bit_cast(float, t);
}
__device__ __forceinline__ float row_sum16(float v) {
    v = dpp_add<0xB1>(v);
    v = dpp_add<0x4E>(v);
    v = dpp_add<0x124>(v);
    v = dpp_add<0x128>(v);
    return v;
}

// ---------------------------------------------------------------------------
// Fused routing pass. Thread = (b_l, p). Per i in the tile:
//   h[j] = W[j,i,p,:]·x[i,:]        (p-lanes -> contiguous 512B, coalesced)
//   bj[j] = row_sum16(v[j,p]·h[j])  (DPP, VALU pipe only)
//   c = softmax_j(bj)               (redundant across p-lanes)
//   sacc[j] += c[j]·h[j]            (same h: W read once per pass)
// No logit tensor: R=1 gets v0, R=2 gets vsum=v0+v1 (b2 = (v0+v1)·hat).
// NOTE: __launch_bounds__(128,4): (128,8) forces VGPR<=32 and spills 210 MB
// to scratch (R6 post-mortem). 4 waves/EU -> VGPR 128 budget, no spill.
// ---------------------------------------------------------------------------
template <int R>
__global__ __launch_bounds__(128, 4) void pass_kernel(
    const float* __restrict__ X,   // [B][I][Q]
    const float* __restrict__ W,   // [J][I][P][Q]
    const float* __restrict__ V,   // R=0: null; R=1: v0; R=2: v0+v1
    float* __restrict__ S)         // [B][J][P] pre-zeroed accumulator
{
    __shared__ float xs[BT * XROW];  // ~2.2 KB

    const int bt = blockIdx.x & (NBT - 1);   // consecutive blocks share i-tile (L2 W reuse)
    const int it = blockIdx.x >> 5;
    const int b0 = bt * BT;
    const int i0 = it * IT;
    const int tid = threadIdx.x;

    // stage x tile: 8 b x 8 i x 8 q = 512 floats = 128 float4, 1 per thread
    {
        const int b_l = tid >> 4;        // 16 float4 per b-row
        const int r   = tid & 15;
        const float4 v4 = ((const float4*)(X + ((size_t)(b0 + b_l) * II + i0) * QQ))[r];
        ((float4*)(xs + b_l * XROW))[r] = v4;
    }
    __syncthreads();

    const int b_l = tid >> 4;
    const int p   = tid & 15;
    const int b   = b0 + b_l;

    float vv[JJ];
    if (R > 0) {
#pragma unroll
        for (int j = 0; j < JJ; ++j)
            vv[j] = V[((size_t)b * JJ + j) * PP + p];
    }

    float sacc[JJ];
#pragma unroll
    for (int j = 0; j < JJ; ++j) sacc[j] = 0.0f;

    for (int i = 0; i < IT; ++i) {
        const float4 a0 = *(const float4*)(xs + b_l * XROW + i * QQ);
        const float4 a1 = *(const float4*)(xs + b_l * XROW + i * QQ + 4);

        float h[JJ];
#pragma unroll
        for (int j = 0; j < JJ; ++j) {
            const float4* wp = (const float4*)(W + (((size_t)j * II + i0 + i) * PP + p) * QQ);
            const float4 w0 = wp[0];
            const float4 w1 = wp[1];
            h[j] = w0.x * a0.x + w0.y * a0.y + w0.z * a0.z + w0.w * a0.w +
                   w1.x * a1.x + w1.y * a1.y + w1.z * a1.z + w1.w * a1.w;
        }

        float c[JJ];
        if (R == 0) {
#pragma unroll
            for (int j = 0; j < JJ; ++j) c[j] = 0.1f;
        } else {
            float bj[JJ];
#pragma unroll
            for (int j = 0; j < JJ; ++j)
                bj[j] = row_sum16(vv[j] * h[j]);   // 10 independent DPP chains
            float m = bj[0];
#pragma unroll
            for (int j = 1; j < JJ; ++j) m = fmaxf(m, bj[j]);
            float sum = 0.0f;
#pragma unroll
            for (int j = 0; j < JJ; ++j) { c[j] = __expf(bj[j] - m); sum += c[j]; }
            const float inv = 1.0f / sum;
#pragma unroll
            for (int j = 0; j < JJ; ++j) c[j] *= inv;
        }

#pragma unroll
        for (int j = 0; j < JJ; ++j) sacc[j] += c[j] * h[j];
    }

#pragma unroll
    for (int j = 0; j < JJ; ++j)
        atomicAdd(&S[((size_t)b * JJ + j) * PP + p], sacc[j]);
}

// ---------------------------------------------------------------------------
// squash row of 16: v = s*|s|^2/(1+|s|^2)/sqrt(|s|^2+1e-7).
// ADD_PREV: out = squash(s) + prev (builds vsum = v1 + v0 for pass 2).
// ZERO_S: re-zero s for the next pass's atomics (replaces a memset dispatch).
// ---------------------------------------------------------------------------
template <int ZERO_S, int ADD_PREV>
__global__ __launch_bounds__(256) void squash_kernel(float* __restrict__ S,
                                                     const float* __restrict__ PREV,
                                                     float* __restrict__ V)
{
    const int idx = blockIdx.x * blockDim.x + threadIdx.x;  // (b*J + j)
    if (idx >= BB * JJ) return;
    float4* sp = (float4*)(S + idx * PP);
    float4 a = sp[0], b4 = sp[1], c4 = sp[2], d4 = sp[3];
    float s2 = a.x * a.x + a.y * a.y + a.z * a.z + a.w * a.w +
               b4.x * b4.x + b4.y * b4.y + b4.z * b4.z + b4.w * b4.w +
               c4.x * c4.x + c4.y * c4.y + c4.z * c4.z + c4.w * c4.w +
               d4.x * d4.x + d4.y * d4.y + d4.z * d4.z + d4.w * d4.w;
    const float scale = s2 / (1.0f + s2) / sqrtf(s2 + 1e-7f);
    a.x *= scale; a.y *= scale; a.z *= scale; a.w *= scale;
    b4.x *= scale; b4.y *= scale; b4.z *= scale; b4.w *= scale;
    c4.x *= scale; c4.y *= scale; c4.z *= scale; c4.w *= scale;
    d4.x *= scale; d4.y *= scale; d4.z *= scale; d4.w *= scale;
    if (ADD_PREV) {
        const float4* pp = (const float4*)(PREV + idx * PP);
        const float4 p0 = pp[0], p1 = pp[1], p2 = pp[2], p3 = pp[3];
        a.x += p0.x; a.y += p0.y; a.z += p0.z; a.w += p0.w;
        b4.x += p1.x; b4.y += p1.y; b4.z += p1.z; b4.w += p1.w;
        c4.x += p2.x; c4.y += p2.y; c4.z += p2.z; c4.w += p2.w;
        d4.x += p3.x; d4.y += p3.y; d4.z += p3.z; d4.w += p3.w;
    }
    float4* vp = (float4*)(V + idx * PP);
    vp[0] = a; vp[1] = b4; vp[2] = c4; vp[3] = d4;
    if (ZERO_S) {
        const float4 z = {0.0f, 0.0f, 0.0f, 0.0f};
        sp[0] = z; sp[1] = z; sp[2] = z; sp[3] = z;
    }
}

extern "C" void kernel_launch(void* const* d_in, const int* in_sizes, int n_in,
                              void* d_out, int out_size, void* d_ws, size_t ws_size,
                              hipStream_t stream)
{
    const float* X = (const float*)d_in[0];  // [256][1152][8]
    const float* W = (const float*)d_in[1];  // [10][1152][16][8]
    float* out = (float*)d_out;              // [256][10][16]

    float* s  = (float*)d_ws;        // 40960 floats
    float* v0 = s + BB * JJ * PP;    // 40960 floats
    float* vs = v0 + BB * JJ * PP;   // 40960 floats (vsum = v0+v1); total 480 KB

    const int grid = NBT * NIT;  // 4608 blocks of 128 threads

    (void)hipMemsetAsync(s, 0, BB * JJ * PP * sizeof(float), stream);
    pass_kernel<0><<<grid, 128, 0, stream>>>(X, W, nullptr, s);
    squash_kernel<1, 0><<<10, 256, 0, stream>>>(s, nullptr, v0);   // v0; s=0
    pass_kernel<1><<<grid, 128, 0, stream>>>(X, W, v0, s);
    squash_kernel<1, 1><<<10, 256, 0, stream>>>(s, v0, vs);        // vs = v1+v0; s=0
    pass_kernel<2><<<grid, 128, 0, stream>>>(X, W, vs, s);
    squash_kernel<0, 0><<<10, 256, 0, stream>>>(s, nullptr, out);  // output
}

// Round 8
// 214.966 us; speedup vs baseline: 1.6038x; 1.0673x over previous
//
#include <hip/hip_runtime.h>

typedef _Float16 h2 __attribute__((ext_vector_type(2)));
typedef _Float16 h8 __attribute__((ext_vector_type(8)));

#define BB 256
#define II 1152
#define QQ 8
#define JJ 10
#define PP 16

#define BT 8             // b per block (128 threads = 8 b-lanes x 16 p-lanes)
#define IT 8             // i per block (grid 4608 for TLP)
#define NBT (BB / BT)    // 32
#define NIT (II / IT)    // 144
#define XRH 72           // halfs per b-row of staged x (64 + 8 pad -> bank-shifted)

#define NW (JJ * II * PP * QQ)   // 1474560 W elements
#define NX (BB * II * QQ)        // 2359296 X elements
#define NS (BB * JJ * PP)        // 40960 S elements per buffer
#define LOG2E 1.4426950408889634f

// ---------------------------------------------------------------------------
// 16-lane row sum via DPP (VALU pipe only).
// ---------------------------------------------------------------------------
template <int CTRL>
__device__ __forceinline__ float dpp_add(float v) {
    int s = __builtin_bit_cast(int, v);
    int t = __builtin_amdgcn_update_dpp(0, s, CTRL, 0xF, 0xF, true);
    return v + __builtin_bit_cast(float, t);
}
__device__ __forceinline__ float row_sum16(float v) {
    v = dpp_add<0xB1>(v);   // xor1 (quad_perm [1,0,3,2])
    v = dpp_add<0x4E>(v);   // xor2 (quad_perm [2,3,0,1])
    v = dpp_add<0x124>(v);  // row_ror:4
    v = dpp_add<0x128>(v);  // row_ror:8
    return v;
}

// 8-element f16 dot with fp32 accumulate: 4 x v_dot2_f32_f16.
__device__ __forceinline__ float dot8(h8 w, h8 x) {
    h2 w0 = __builtin_shufflevector(w, w, 0, 1), w1 = __builtin_shufflevector(w, w, 2, 3);
    h2 w2 = __builtin_shufflevector(w, w, 4, 5), w3 = __builtin_shufflevector(w, w, 6, 7);
    h2 x0 = __builtin_shufflevector(x, x, 0, 1), x1 = __builtin_shufflevector(x, x, 2, 3);
    h2 x2 = __builtin_shufflevector(x, x, 4, 5), x3 = __builtin_shufflevector(x, x, 6, 7);
    float acc = __builtin_amdgcn_fdot2(w0, x0, 0.0f, false);
    acc = __builtin_amdgcn_fdot2(w1, x1, acc, false);
    acc = __builtin_amdgcn_fdot2(w2, x2, acc, false);
    acc = __builtin_amdgcn_fdot2(w3, x3, acc, false);
    return acc;
}

// ---------------------------------------------------------------------------
// prep: W,X fp32 -> f16 copies; zero S0/S1/S2. One dispatch.
// ---------------------------------------------------------------------------
__global__ __launch_bounds__(256) void prep_kernel(
    const float* __restrict__ X, const float* __restrict__ W,
    _Float16* __restrict__ Xh, _Float16* __restrict__ Wh,
    float* __restrict__ S)   // 3*NS floats
{
    const int g = blockIdx.x * 256 + threadIdx.x;
    const int stride = gridDim.x * 256;
    for (int k = g; k < NW; k += stride) Wh[k] = (_Float16)W[k];
    for (int k = g; k < NX; k += stride) Xh[k] = (_Float16)X[k];
    for (int k = g; k < 3 * NS; k += stride) S[k] = 0.0f;
}

// ---------------------------------------------------------------------------
// Fused routing pass (f16 inputs). Thread = (b_l, p).
// Block prologue (R>0): vv[j] = squash(Sprev[b,j,:])[p] * log2e, computed
// inline via DPP (n2 = row_sum16(sp^2)). R==1,it==0 blocks persist v0;
// R==2 adds v0 so logits use (v0+v1)·hat (cumulative b without a logit tensor).
// Per i: h[j] = dot8(W[j,i,p,:], x) ; bj = row_sum16(vv*h) ; e = exp2(bj) ;
//        sacc[j] += (e*inv)*h[j].  (no max-sub: logits bounded ~±3)
// R==0: c uniform -> sacc[j] += h[j], scaled 0.1 at the atomic.
// ---------------------------------------------------------------------------
template <int R>
__global__ __launch_bounds__(128, 4) void pass_kernel(
    const _Float16* __restrict__ Xh,  // [B][I][Q] f16
    const _Float16* __restrict__ Wh,  // [J][I][P][Q] f16
    const float* __restrict__ Sprev,  // [B][J][P] raw s from prev pass (R>0)
    float* __restrict__ V0,           // [B][J][P] v0 buffer (R1 writes, R2 reads)
    float* __restrict__ Sout)         // [B][J][P] pre-zeroed accumulator
{
    __shared__ _Float16 xs[BT * XRH];  // 1152 B

    const int bt = blockIdx.x & (NBT - 1);
    const int it = blockIdx.x >> 5;
    const int b0 = bt * BT;
    const int i0 = it * IT;
    const int tid = threadIdx.x;

    // stage x tile: 8 b x 8 i x 8 q f16 = 1 KB; 8 B per thread
    {
        const int b_l = tid >> 4;
        const int r   = tid & 15;
        *(uint2*)(xs + b_l * XRH + r * 4) =
            *(const uint2*)(Xh + ((size_t)(b0 + b_l) * II + i0) * QQ + r * 4);
    }
    __syncthreads();

    const int b_l = tid >> 4;
    const int p   = tid & 15;
    const int b   = b0 + b_l;

    // inline squash of Sprev -> vv (pre-scaled by log2e)
    float vv[JJ];
    if (R > 0) {
#pragma unroll
        for (int j = 0; j < JJ; ++j) {
            const float sp = Sprev[((size_t)b * JJ + j) * PP + p];
            const float n2 = row_sum16(sp * sp);
            const float scale = n2 * __builtin_amdgcn_rcpf(1.0f + n2)
                                   * __builtin_amdgcn_rsqf(n2 + 1e-7f);
            float v = sp * scale;                       // v_prev[b,j,p]
            if (R == 1) {
                if (it == 0) V0[((size_t)b * JJ + j) * PP + p] = v;
            } else {
                v += V0[((size_t)b * JJ + j) * PP + p]; // v0 + v1
            }
            vv[j] = v * LOG2E;
        }
    }

    float sacc[JJ];
#pragma unroll
    for (int j = 0; j < JJ; ++j) sacc[j] = 0.0f;

#pragma unroll
    for (int i = 0; i < IT; ++i) {
        const h8 x8 = *(const h8*)(xs + b_l * XRH + i * QQ);

        float h[JJ];
#pragma unroll
        for (int j = 0; j < JJ; ++j) {
            const h8 w8 = *(const h8*)(Wh + (((size_t)j * II + i0 + i) * PP + p) * QQ);
            h[j] = dot8(w8, x8);
        }

        if (R == 0) {
#pragma unroll
            for (int j = 0; j < JJ; ++j) sacc[j] += h[j];
        } else {
            float e[JJ];
            float sum = 0.0f;
#pragma unroll
            for (int j = 0; j < JJ; ++j) {
                const float bj = row_sum16(vv[j] * h[j]);  // log2-scaled logit
                e[j] = exp2f(bj);
                sum += e[j];
            }
            const float inv = __builtin_amdgcn_rcpf(sum);
#pragma unroll
            for (int j = 0; j < JJ; ++j) sacc[j] += (e[j] * inv) * h[j];
        }
    }

#pragma unroll
    for (int j = 0; j < JJ; ++j)
        atomicAdd(&Sout[((size_t)b * JJ + j) * PP + p],
                  (R == 0) ? 0.1f * sacc[j] : sacc[j]);
}

// ---------------------------------------------------------------------------
// final output squash (fp32 precise): out = squash(S2)
// ---------------------------------------------------------------------------
__global__ __launch_bounds__(256) void squash_out_kernel(const float* __restrict__ S,
                                                         float* __restrict__ V)
{
    const int idx = blockIdx.x * blockDim.x + threadIdx.x;  // (b*J + j)
    if (idx >= BB * JJ) return;
    const float4* sp = (const float4*)(S + idx * PP);
    float4 a = sp[0], b4 = sp[1], c4 = sp[2], d4 = sp[3];
    float s2 = a.x * a.x + a.y * a.y + a.z * a.z + a.w * a.w +
               b4.x * b4.x + b4.y * b4.y + b4.z * b4.z + b4.w * b4.w +
               c4.x * c4.x + c4.y * c4.y + c4.z * c4.z + c4.w * c4.w +
               d4.x * d4.x + d4.y * d4.y + d4.z * d4.z + d4.w * d4.w;
    const float scale = s2 / (1.0f + s2) / sqrtf(s2 + 1e-7f);
    a.x *= scale; a.y *= scale; a.z *= scale; a.w *= scale;
    b4.x *= scale; b4.y *= scale; b4.z *= scale; b4.w *= scale;
    c4.x *= scale; c4.y *= scale; c4.z *= scale; c4.w *= scale;
    d4.x *= scale; d4.y *= scale; d4.z *= scale; d4.w *= scale;
    float4* vp = (float4*)(V + idx * PP);
    vp[0] = a; vp[1] = b4; vp[2] = c4; vp[3] = d4;
}

extern "C" void kernel_launch(void* const* d_in, const int* in_sizes, int n_in,
                              void* d_out, int out_size, void* d_ws, size_t ws_size,
                              hipStream_t stream)
{
    const float* X = (const float*)d_in[0];  // [256][1152][8]
    const float* W = (const float*)d_in[1];  // [10][1152][16][8]
    float* out = (float*)d_out;              // [256][10][16]

    _Float16* Xh = (_Float16*)d_ws;          // NX halfs (4.72 MB)
    _Float16* Wh = Xh + NX;                  // NW halfs (2.95 MB)
    float* S0 = (float*)(Wh + NW);           // NS floats
    float* S1 = S0 + NS;
    float* S2 = S1 + NS;
    float* v0 = S2 + NS;                     // NS floats; total ~8.3 MB

    const int grid = NBT * NIT;  // 4608 blocks of 128 threads

    prep_kernel<<<1024, 256, 0, stream>>>(X, W, Xh, Wh, S0);  // S0,S1,S2 contiguous
    pass_kernel<0><<<grid, 128, 0, stream>>>(Xh, Wh, nullptr, nullptr, S0);
    pass_kernel<1><<<grid, 128, 0, stream>>>(Xh, Wh, S0, v0, S1);
    pass_kernel<2><<<grid, 128, 0, stream>>>(Xh, Wh, S1, v0, S2);
    squash_out_kernel<<<10, 256, 0, stream>>>(S2, out);
}